// Round 1
// baseline (267.959 us; speedup 1.0000x reference)
//
#include <hip/hip_runtime.h>

// VectorCollapseEngine: 6 affine-in-h layers collapsed to one fused pass.
// h_{l+1} = a*h_l + sum_k c_k dir_k  =>  h_final = A*h0 + sum_k W_k anchor_k.
// Per row we only need s=||h||^2 and d_k=h.dir_k; recurrences use the anchor
// Gram matrix. One HBM read of h0, one HBM write of h_final, tiny traces.

constexpr int DIM = 4096;
constexpr int BATCH = 8192;
constexpr int NLAYERS = 6;
constexpr int TPB = 256;
constexpr int VPT = DIM / (TPB * 4);  // float4 chunks per thread = 4

constexpr size_t HOUT = (size_t)BATCH * DIM;            // h_final elems
constexpr size_t TRACE = (size_t)NLAYERS * BATCH * 3;   // per-trace elems
constexpr size_t OFF_ALIGN = HOUT;
constexpr size_t OFF_DIV   = HOUT + TRACE;
constexpr size_t OFF_TENS  = HOUT + 2 * TRACE;

__device__ __forceinline__ float wave_red(float v) {
#pragma unroll
  for (int off = 32; off > 0; off >>= 1) v += __shfl_down(v, off, 64);
  return v;  // lane 0 holds the wave sum
}

__global__ __launch_bounds__(TPB) void collapse_kernel(
    const float* __restrict__ h0,
    const float* __restrict__ an0,
    const float* __restrict__ an1,
    const float* __restrict__ an2,
    float* __restrict__ out) {
  const int b = blockIdx.x;
  const int tid = threadIdx.x;
  const float* hrow = h0 + (size_t)b * DIM;

  // ---- pass 1: load h row + anchors into registers, accumulate 10 dots ----
  float4 hv[VPT], a0v[VPT], a1v[VPT], a2v[VPT];
  float r[10];  // s, d0,d1,d2, n0sq,n1sq,n2sq, g01,g02,g12
#pragma unroll
  for (int i = 0; i < 10; ++i) r[i] = 0.f;

#pragma unroll
  for (int j = 0; j < VPT; ++j) {
    const int idx = (tid + j * TPB) * 4;
    hv[j]  = *(const float4*)(hrow + idx);
    a0v[j] = *(const float4*)(an0 + idx);
    a1v[j] = *(const float4*)(an1 + idx);
    a2v[j] = *(const float4*)(an2 + idx);
    const float4 h = hv[j], x = a0v[j], y = a1v[j], z = a2v[j];
    r[0] += h.x*h.x + h.y*h.y + h.z*h.z + h.w*h.w;
    r[1] += h.x*x.x + h.y*x.y + h.z*x.z + h.w*x.w;
    r[2] += h.x*y.x + h.y*y.y + h.z*y.z + h.w*y.w;
    r[3] += h.x*z.x + h.y*z.y + h.z*z.z + h.w*z.w;
    r[4] += x.x*x.x + x.y*x.y + x.z*x.z + x.w*x.w;
    r[5] += y.x*y.x + y.y*y.y + y.z*y.z + y.w*y.w;
    r[6] += z.x*z.x + z.y*z.y + z.z*z.z + z.w*z.w;
    r[7] += x.x*y.x + x.y*y.y + x.z*y.z + x.w*y.w;
    r[8] += x.x*z.x + x.y*z.y + x.z*z.z + x.w*z.w;
    r[9] += y.x*z.x + y.y*z.y + y.z*z.z + y.w*z.w;
  }

  // ---- block reduction (4 waves) ----
  __shared__ float lds[4][10];
  const int lane = tid & 63, wv = tid >> 6;
#pragma unroll
  for (int i = 0; i < 10; ++i) r[i] = wave_red(r[i]);
  if (lane == 0) {
#pragma unroll
    for (int i = 0; i < 10; ++i) lds[wv][i] = r[i];
  }
  __syncthreads();
#pragma unroll
  for (int i = 0; i < 10; ++i)
    r[i] = lds[0][i] + lds[1][i] + lds[2][i] + lds[3][i];

  // ---- scalar setup: anchor norms + Gram of normalized dirs ----
  const float n0 = fmaxf(sqrtf(r[4]), 1e-12f);
  const float n1 = fmaxf(sqrtf(r[5]), 1e-12f);
  const float n2 = fmaxf(sqrtf(r[6]), 1e-12f);
  float G[3][3];
  G[0][0] = r[4] / (n0 * n0);
  G[1][1] = r[5] / (n1 * n1);
  G[2][2] = r[6] / (n2 * n2);
  G[0][1] = G[1][0] = r[7] / (n0 * n1);
  G[0][2] = G[2][0] = r[8] / (n0 * n2);
  G[1][2] = G[2][1] = r[9] / (n1 * n2);

  const float str[3] = {0.1f, 0.1f, 0.05f};
  float s = r[0];
  float d[3] = {r[1] / n0, r[2] / n1, r[3] / n2};
  float A = 1.f;
  float B[3] = {0.f, 0.f, 0.f};

  // ---- 6-layer scalar recurrence (redundant on all threads; cheap) ----
#pragma unroll
  for (int l = 0; l < NLAYERS; ++l) {
    const float hn = fmaxf(sqrtf(s), 1e-12f);
    float al[3], dv[3], c[3];
#pragma unroll
    for (int k = 0; k < 3; ++k) {
      al[k] = d[k] / hn;
      dv[k] = 1.f - al[k];
      const float rr = fmaxf(sqrtf(s - 2.f * d[k] + G[k][k]), 1e-12f);
      c[k] = str[k] * dv[k] / rr;
    }
    if (tid == 0) {
#pragma unroll
      for (int k = 0; k < 3; ++k) {
        const size_t o = (size_t)l * (BATCH * 3) + (size_t)b * 3 + k;
        out[OFF_ALIGN + o] = al[k];
        out[OFF_DIV + o]   = dv[k];
        out[OFF_TENS + o]  = fmaxf(dv[k], 0.f);
      }
    }
    const float a = 1.f - (c[0] + c[1] + c[2]);
    float dn[3];
#pragma unroll
    for (int j = 0; j < 3; ++j)
      dn[j] = a * d[j] + c[0] * G[0][j] + c[1] * G[1][j] + c[2] * G[2][j];
    float sn = a * a * s + 2.f * a * (c[0]*d[0] + c[1]*d[1] + c[2]*d[2]);
#pragma unroll
    for (int k = 0; k < 3; ++k)
#pragma unroll
      for (int j = 0; j < 3; ++j) sn += c[k] * c[j] * G[k][j];
    A = a * A;
#pragma unroll
    for (int j = 0; j < 3; ++j) B[j] = a * B[j] + c[j];
    s = sn;
#pragma unroll
    for (int j = 0; j < 3; ++j) d[j] = dn[j];
    const float hn2 = sqrtf(s);
    if (hn2 > 10.0f) {
      const float sc = 10.0f / (hn2 + 1e-8f);
      A *= sc;
#pragma unroll
      for (int j = 0; j < 3; ++j) { B[j] *= sc; d[j] *= sc; }
      s *= sc * sc;
    }
  }

  // ---- pass 2: h_final = A*h0 + sum_k (B_k/n_k)*anchor_k, from registers ----
  const float w0 = B[0] / n0, w1 = B[1] / n1, w2 = B[2] / n2;
  float* orow = out + (size_t)b * DIM;
#pragma unroll
  for (int j = 0; j < VPT; ++j) {
    const int idx = (tid + j * TPB) * 4;
    const float4 h = hv[j], x = a0v[j], y = a1v[j], z = a2v[j];
    float4 o;
    o.x = A * h.x + w0 * x.x + w1 * y.x + w2 * z.x;
    o.y = A * h.y + w0 * x.y + w1 * y.y + w2 * z.y;
    o.z = A * h.z + w0 * x.z + w1 * y.z + w2 * z.z;
    o.w = A * h.w + w0 * x.w + w1 * y.w + w2 * z.w;
    *(float4*)(orow + idx) = o;
  }
}

extern "C" void kernel_launch(void* const* d_in, const int* in_sizes, int n_in,
                              void* d_out, int out_size, void* d_ws, size_t ws_size,
                              hipStream_t stream) {
  const float* h0  = (const float*)d_in[0];
  const float* an0 = (const float*)d_in[1];
  const float* an1 = (const float*)d_in[2];
  const float* an2 = (const float*)d_in[3];
  float* out = (float*)d_out;
  collapse_kernel<<<BATCH, TPB, 0, stream>>>(h0, an0, an1, an2, out);
}

// Round 2
// 259.743 us; speedup vs baseline: 1.0316x; 1.0316x over previous
//
#include <hip/hip_runtime.h>

// VectorCollapseEngine: 6 affine-in-h layers collapsed to one fused pass.
// h_{l+1} = a*h_l + sum_k c_k dir_k  =>  h_final = A*h0 + sum_k W_k anchor_k.
// R2: (1) anchor Gram/norms hoisted to a one-block setup kernel (they are
// row-independent); (2) the 6-layer scalar recurrence runs on ONE lane per
// block (broadcast via LDS) instead of redundantly on all 256 threads.
// R1 showed VALUBusy=90% / HBM=22% — instruction count was the bottleneck.

constexpr int DIM = 4096;
constexpr int BATCH = 8192;
constexpr int NLAYERS = 6;
constexpr int TPB = 256;
constexpr int VPT = DIM / (TPB * 4);  // float4 chunks per thread = 4

constexpr size_t HOUT = (size_t)BATCH * DIM;            // h_final elems
constexpr size_t TRACE = (size_t)NLAYERS * BATCH * 3;   // per-trace elems
constexpr size_t OFF_ALIGN = HOUT;
constexpr size_t OFF_DIV   = HOUT + TRACE;
constexpr size_t OFF_TENS  = HOUT + 2 * TRACE;

__device__ __forceinline__ float wave_red(float v) {
#pragma unroll
  for (int off = 32; off > 0; off >>= 1) v += __shfl_down(v, off, 64);
  return v;  // lane 0 holds the wave sum
}

// ---- setup: anchor norms + Gram of normalized dirs -> ws[0..8] ----
// ws layout: [n0, n1, n2, G01, G02, G12, G00, G11, G22]
__global__ __launch_bounds__(TPB) void gram_kernel(
    const float* __restrict__ an0, const float* __restrict__ an1,
    const float* __restrict__ an2, float* __restrict__ ws) {
  const int tid = threadIdx.x;
  float r[6];
#pragma unroll
  for (int i = 0; i < 6; ++i) r[i] = 0.f;
#pragma unroll
  for (int j = 0; j < VPT; ++j) {
    const int idx = (tid + j * TPB) * 4;
    const float4 x = *(const float4*)(an0 + idx);
    const float4 y = *(const float4*)(an1 + idx);
    const float4 z = *(const float4*)(an2 + idx);
    r[0] += x.x*x.x + x.y*x.y + x.z*x.z + x.w*x.w;
    r[1] += y.x*y.x + y.y*y.y + y.z*y.z + y.w*y.w;
    r[2] += z.x*z.x + z.y*z.y + z.z*z.z + z.w*z.w;
    r[3] += x.x*y.x + x.y*y.y + x.z*y.z + x.w*y.w;
    r[4] += x.x*z.x + x.y*z.y + x.z*z.z + x.w*z.w;
    r[5] += y.x*z.x + y.y*z.y + y.z*z.z + y.w*z.w;
  }
  __shared__ float lds[4][6];
  const int lane = tid & 63, wv = tid >> 6;
#pragma unroll
  for (int i = 0; i < 6; ++i) r[i] = wave_red(r[i]);
  if (lane == 0) {
#pragma unroll
    for (int i = 0; i < 6; ++i) lds[wv][i] = r[i];
  }
  __syncthreads();
  if (tid == 0) {
#pragma unroll
    for (int i = 0; i < 6; ++i)
      r[i] = lds[0][i] + lds[1][i] + lds[2][i] + lds[3][i];
    const float n0 = fmaxf(sqrtf(r[0]), 1e-12f);
    const float n1 = fmaxf(sqrtf(r[1]), 1e-12f);
    const float n2 = fmaxf(sqrtf(r[2]), 1e-12f);
    ws[0] = n0; ws[1] = n1; ws[2] = n2;
    ws[3] = r[3] / (n0 * n1);
    ws[4] = r[4] / (n0 * n2);
    ws[5] = r[5] / (n1 * n2);
    ws[6] = r[0] / (n0 * n0);
    ws[7] = r[1] / (n1 * n1);
    ws[8] = r[2] / (n2 * n2);
  }
}

__global__ __launch_bounds__(TPB) void collapse_kernel(
    const float* __restrict__ h0,
    const float* __restrict__ an0,
    const float* __restrict__ an1,
    const float* __restrict__ an2,
    const float* __restrict__ ws,
    float* __restrict__ out) {
  const int b = blockIdx.x;
  const int tid = threadIdx.x;
  const float* hrow = h0 + (size_t)b * DIM;

  // ---- pass 1: row dots {|h|^2, h.a0, h.a1, h.a2}; h stays in registers ----
  float4 hv[VPT];
  float r[4] = {0.f, 0.f, 0.f, 0.f};
#pragma unroll
  for (int j = 0; j < VPT; ++j) {
    const int idx = (tid + j * TPB) * 4;
    hv[j] = *(const float4*)(hrow + idx);
    const float4 x = *(const float4*)(an0 + idx);
    const float4 y = *(const float4*)(an1 + idx);
    const float4 z = *(const float4*)(an2 + idx);
    const float4 h = hv[j];
    r[0] += h.x*h.x + h.y*h.y + h.z*h.z + h.w*h.w;
    r[1] += h.x*x.x + h.y*x.y + h.z*x.z + h.w*x.w;
    r[2] += h.x*y.x + h.y*y.y + h.z*y.z + h.w*y.w;
    r[3] += h.x*z.x + h.y*z.y + h.z*z.z + h.w*z.w;
  }

  // ---- block reduction (4 waves, 4 values) ----
  __shared__ float lds[4][4];
  __shared__ float coef[4];  // A, w0, w1, w2
  const int lane = tid & 63, wv = tid >> 6;
#pragma unroll
  for (int i = 0; i < 4; ++i) r[i] = wave_red(r[i]);
  if (lane == 0) {
#pragma unroll
    for (int i = 0; i < 4; ++i) lds[wv][i] = r[i];
  }
  __syncthreads();

  // ---- recurrence on ONE lane; ~700 VALU slots, issued once per block ----
  if (tid == 0) {
#pragma unroll
    for (int i = 0; i < 4; ++i)
      r[i] = lds[0][i] + lds[1][i] + lds[2][i] + lds[3][i];
    const float n0 = ws[0], n1 = ws[1], n2 = ws[2];
    float G[3][3];
    G[0][1] = G[1][0] = ws[3];
    G[0][2] = G[2][0] = ws[4];
    G[1][2] = G[2][1] = ws[5];
    G[0][0] = ws[6]; G[1][1] = ws[7]; G[2][2] = ws[8];

    const float str[3] = {0.1f, 0.1f, 0.05f};
    float s = r[0];
    float d[3] = {r[1] / n0, r[2] / n1, r[3] / n2};
    float A = 1.f;
    float B[3] = {0.f, 0.f, 0.f};

#pragma unroll
    for (int l = 0; l < NLAYERS; ++l) {
      const float hn = fmaxf(sqrtf(s), 1e-12f);
      float al[3], dv[3], c[3];
#pragma unroll
      for (int k = 0; k < 3; ++k) {
        al[k] = d[k] / hn;
        dv[k] = 1.f - al[k];
        const float rr = fmaxf(sqrtf(s - 2.f * d[k] + G[k][k]), 1e-12f);
        c[k] = str[k] * dv[k] / rr;
      }
#pragma unroll
      for (int k = 0; k < 3; ++k) {
        const size_t o = (size_t)l * (BATCH * 3) + (size_t)b * 3 + k;
        out[OFF_ALIGN + o] = al[k];
        out[OFF_DIV + o]   = dv[k];
        out[OFF_TENS + o]  = fmaxf(dv[k], 0.f);
      }
      const float a = 1.f - (c[0] + c[1] + c[2]);
      float dn[3];
#pragma unroll
      for (int j = 0; j < 3; ++j)
        dn[j] = a * d[j] + c[0] * G[0][j] + c[1] * G[1][j] + c[2] * G[2][j];
      float sn = a * a * s + 2.f * a * (c[0]*d[0] + c[1]*d[1] + c[2]*d[2]);
#pragma unroll
      for (int k = 0; k < 3; ++k)
#pragma unroll
        for (int j = 0; j < 3; ++j) sn += c[k] * c[j] * G[k][j];
      A = a * A;
#pragma unroll
      for (int j = 0; j < 3; ++j) B[j] = a * B[j] + c[j];
      s = sn;
#pragma unroll
      for (int j = 0; j < 3; ++j) d[j] = dn[j];
      const float hn2 = sqrtf(s);
      if (hn2 > 10.0f) {
        const float sc = 10.0f / (hn2 + 1e-8f);
        A *= sc;
#pragma unroll
        for (int j = 0; j < 3; ++j) { B[j] *= sc; d[j] *= sc; }
        s *= sc * sc;
      }
    }
    coef[0] = A;
    coef[1] = B[0] / n0;
    coef[2] = B[1] / n1;
    coef[3] = B[2] / n2;
  }
  __syncthreads();
  const float A = coef[0], w0 = coef[1], w1 = coef[2], w2 = coef[3];

  // ---- pass 2: h from registers; anchors re-read (L1/L2-hot, 48KB) ----
  float* orow = out + (size_t)b * DIM;
#pragma unroll
  for (int j = 0; j < VPT; ++j) {
    const int idx = (tid + j * TPB) * 4;
    const float4 x = *(const float4*)(an0 + idx);
    const float4 y = *(const float4*)(an1 + idx);
    const float4 z = *(const float4*)(an2 + idx);
    const float4 h = hv[j];
    float4 o;
    o.x = A * h.x + w0 * x.x + w1 * y.x + w2 * z.x;
    o.y = A * h.y + w0 * x.y + w1 * y.y + w2 * z.y;
    o.z = A * h.z + w0 * x.z + w1 * y.z + w2 * z.z;
    o.w = A * h.w + w0 * x.w + w1 * y.w + w2 * z.w;
    *(float4*)(orow + idx) = o;
  }
}

extern "C" void kernel_launch(void* const* d_in, const int* in_sizes, int n_in,
                              void* d_out, int out_size, void* d_ws, size_t ws_size,
                              hipStream_t stream) {
  const float* h0  = (const float*)d_in[0];
  const float* an0 = (const float*)d_in[1];
  const float* an1 = (const float*)d_in[2];
  const float* an2 = (const float*)d_in[3];
  float* out = (float*)d_out;
  float* ws  = (float*)d_ws;
  gram_kernel<<<1, TPB, 0, stream>>>(an0, an1, an2, ws);
  collapse_kernel<<<BATCH, TPB, 0, stream>>>(h0, an0, an1, an2, ws, out);
}